// Round 1
// baseline (783.773 us; speedup 1.0000x reference)
//
#include <hip/hip_runtime.h>

typedef __attribute__((ext_vector_type(8))) short s16x8;
typedef __attribute__((ext_vector_type(8))) __bf16 bf16x8;
typedef __attribute__((ext_vector_type(4))) float f32x4;

#define S_LEN 2048
#define KDIM  4096
// softmax scale * log2(e): (1/sqrt(128)) * 1.4426950408889634
#define CSOFT 0.12751743f

__device__ __forceinline__ unsigned short f2bf(float f) {
  unsigned u = __builtin_bit_cast(unsigned, f);
  u += 0x7fffu + ((u >> 16) & 1u);
  return (unsigned short)(u >> 16);
}

__device__ __forceinline__ f32x4 mfma_bf16(s16x8 a, s16x8 b, f32x4 c) {
  return __builtin_amdgcn_mfma_f32_16x16x32_bf16(
      __builtin_bit_cast(bf16x8, a), __builtin_bit_cast(bf16x8, b), c, 0, 0, 0);
}

// ---------------- fp32 -> bf16 convert ----------------
__global__ void cvt_bf16(const float* __restrict__ in,
                         unsigned short* __restrict__ out, int n8) {
  int i = blockIdx.x * 256 + threadIdx.x;
  if (i >= n8) return;
  const float* p = in + (size_t)i * 8;
  f32x4 a = *(const f32x4*)(p);
  f32x4 b = *(const f32x4*)(p + 4);
  s16x8 v;
  v[0] = (short)f2bf(a[0]); v[1] = (short)f2bf(a[1]);
  v[2] = (short)f2bf(a[2]); v[3] = (short)f2bf(a[3]);
  v[4] = (short)f2bf(b[0]); v[5] = (short)f2bf(b[1]);
  v[6] = (short)f2bf(b[2]); v[7] = (short)f2bf(b[3]);
  *(s16x8*)(out + (size_t)i * 8) = v;
}

// ---------------- GEMM: C[M,N] = A[M,K] @ B[N,K]^T, bf16 in, epilogues ----
// EPI: 0 = Q (rope, store [b][32+h][s][hd]), 1 = K (rope, store [b][8][s][hd]),
//      2 = V (store transposed [b][8][hd][s]),  3 = O (store fp32 token-major)
template <int EPI, int N, bool B_FP32>
__global__ __launch_bounds__(256, 2)
void gemm_bt(const unsigned short* __restrict__ A,
             const float* __restrict__ Bw32,
             const unsigned short* __restrict__ Bw16,
             void* __restrict__ Out,
             const float* __restrict__ cosT,
             const float* __restrict__ sinT) {
  const int K = KDIM;
  const int tid = threadIdx.x;
  const int lane = tid & 63, wid = tid >> 6;
  const int l15 = lane & 15, l4 = lane >> 4;
  const int nct = N / 128;
  const int ct = blockIdx.x % nct, rt = blockIdx.x / nct;
  const int row0 = rt * 128, col0 = ct * 128;
  const int wr = wid >> 1, wc = wid & 1;

  __shared__ __align__(16) unsigned short As[128 * 32];
  __shared__ __align__(16) unsigned short Bs[128 * 32];

  f32x4 acc[4][4];
#pragma unroll
  for (int i = 0; i < 4; i++)
#pragma unroll
    for (int j = 0; j < 4; j++) acc[i][j] = f32x4{0.f, 0.f, 0.f, 0.f};

  for (int kt = 0; kt < K; kt += 32) {
    // stage A (bf16 source): 512 chunks of 16B, swizzled
#pragma unroll
    for (int j = 0; j < 2; j++) {
      int ch = tid + 256 * j;
      int r = ch >> 2, c = ch & 3;
      s16x8 v = *(const s16x8*)(A + (size_t)(row0 + r) * K + kt + c * 8);
      int sw = c ^ ((r >> 1) & 3);
      *(s16x8*)((char*)As + r * 64 + sw * 16) = v;
    }
    // stage B
#pragma unroll
    for (int j = 0; j < 2; j++) {
      int ch = tid + 256 * j;
      int r = ch >> 2, c = ch & 3;
      s16x8 v;
      if (B_FP32) {
        const float* src = Bw32 + (size_t)(col0 + r) * K + kt + c * 8;
        f32x4 f0 = *(const f32x4*)(src);
        f32x4 f1 = *(const f32x4*)(src + 4);
        v[0] = (short)f2bf(f0[0]); v[1] = (short)f2bf(f0[1]);
        v[2] = (short)f2bf(f0[2]); v[3] = (short)f2bf(f0[3]);
        v[4] = (short)f2bf(f1[0]); v[5] = (short)f2bf(f1[1]);
        v[6] = (short)f2bf(f1[2]); v[7] = (short)f2bf(f1[3]);
      } else {
        v = *(const s16x8*)(Bw16 + (size_t)(col0 + r) * K + kt + c * 8);
      }
      int sw = c ^ ((r >> 1) & 3);
      *(s16x8*)((char*)Bs + r * 64 + sw * 16) = v;
    }
    __syncthreads();

    s16x8 af[4], bfr[4];
#pragma unroll
    for (int mi = 0; mi < 4; mi++) {
      int r = wr * 64 + mi * 16 + l15;
      int sw = l4 ^ ((r >> 1) & 3);
      af[mi] = *(const s16x8*)((char*)As + r * 64 + sw * 16);
    }
#pragma unroll
    for (int ni = 0; ni < 4; ni++) {
      int r = wc * 64 + ni * 16 + l15;
      int sw = l4 ^ ((r >> 1) & 3);
      bfr[ni] = *(const s16x8*)((char*)Bs + r * 64 + sw * 16);
    }
#pragma unroll
    for (int mi = 0; mi < 4; mi++)
#pragma unroll
      for (int ni = 0; ni < 4; ni++)
        acc[mi][ni] = mfma_bf16(af[mi], bfr[ni], acc[mi][ni]);
    __syncthreads();
  }

  // epilogue
#pragma unroll
  for (int mi = 0; mi < 4; mi++) {
#pragma unroll
    for (int ni = 0; ni < 4; ni++) {
      f32x4 v = acc[mi][ni];
      int rowb = row0 + wr * 64 + mi * 16 + l4 * 4;  // token base (4 rows)
      int col = col0 + wc * 64 + ni * 16 + l15;
      if (EPI == 3) {
        float* o = (float*)Out;
#pragma unroll
        for (int r = 0; r < 4; r++) o[(size_t)(rowb + r) * 4096 + col] = v[r];
      } else {
        if (EPI != 2) {  // RoPE for Q,K
          float vp[4];
#pragma unroll
          for (int r = 0; r < 4; r++) vp[r] = __shfl_xor(v[r], 1, 64);
          bool odd = lane & 1;
          int fi = (col & 127) >> 1;
#pragma unroll
          for (int r = 0; r < 4; r++) {
            int n = rowb + r, s = n >> 1;
            float c = cosT[s * 64 + fi], sn = sinT[s * 64 + fi];
            v[r] = odd ? (vp[r] * sn + v[r] * c) : (v[r] * c - vp[r] * sn);
          }
        }
        unsigned short* o = (unsigned short*)Out;
        int hh = col >> 7, hd = col & 127;
#pragma unroll
        for (int r = 0; r < 4; r++) {
          int n = rowb + r, s = n >> 1, b = n & 1;
          size_t idx;
          if (EPI == 0)      idx = ((size_t)(b * 32 + hh) * 2048 + s) * 128 + hd;
          else if (EPI == 1) idx = ((size_t)(b * 8 + hh) * 2048 + s) * 128 + hd;
          else               idx = ((size_t)(b * 8 + hh) * 128 + hd) * 2048 + s;
          o[idx] = f2bf(v[r]);
        }
      }
    }
  }
}

// ---------------- Flash attention (causal, GQA) ----------------
// grid: 16 q-tiles x 32 heads x 2 batch.  block: 256 threads (4 waves x 32 q rows)
__global__ __launch_bounds__(256, 2)
void attn_fwd(const unsigned short* __restrict__ Qa,
              const unsigned short* __restrict__ Ka,
              const unsigned short* __restrict__ Vt,
              unsigned short* __restrict__ AO) {
  int bid = blockIdx.x;
  int qt = bid & 15;
  int h = (bid >> 4) & 31;
  int b = bid >> 9;
  int kvh = h >> 2;
  int tid = threadIdx.x, lane = tid & 63, wid = tid >> 6;
  int l15 = lane & 15, l4 = lane >> 4;
  int q0 = qt * 128, qr0 = q0 + wid * 32;

  __shared__ __align__(16) unsigned short Ks[64 * 128];   // [kv][hd] swizzled
  __shared__ __align__(16) unsigned short Vs[128 * 64];   // [hd][kv] swizzled
  __shared__ __align__(16) unsigned short Ps[4][32 * 64]; // per-wave P

  const unsigned short* Qp = Qa + ((size_t)(b * 32 + h) * 2048) * 128;
  const unsigned short* Kp = Ka + ((size_t)(b * 8 + kvh) * 2048) * 128;
  const unsigned short* Vp = Vt + ((size_t)(b * 8 + kvh) * 128) * 2048;

  // Q fragments in registers: rows qr0..qr0+31, full 128 hd
  s16x8 qf[2][4];
#pragma unroll
  for (int mi = 0; mi < 2; mi++)
#pragma unroll
    for (int ks = 0; ks < 4; ks++)
      qf[mi][ks] = *(const s16x8*)(Qp + (size_t)(qr0 + mi * 16 + l15) * 128 +
                                   ks * 32 + l4 * 8);

  f32x4 o[2][8];
#pragma unroll
  for (int mi = 0; mi < 2; mi++)
#pragma unroll
    for (int nb = 0; nb < 8; nb++) o[mi][nb] = f32x4{0.f, 0.f, 0.f, 0.f};
  float m[2][4], lsum[2][4];
#pragma unroll
  for (int mi = 0; mi < 2; mi++)
#pragma unroll
    for (int pr = 0; pr < 4; pr++) { m[mi][pr] = -1e30f; lsum[mi][pr] = 0.f; }

  int nt = q0 / 64 + 2;
  for (int t = 0; t < nt; t++) {
    int s0 = t * 64;
    // stage K tile: contiguous 16KB; 1024 x 16B chunks, 4/thread
    const unsigned short* ktp = Kp + (size_t)s0 * 128;
#pragma unroll
    for (int j = 0; j < 4; j++) {
      int ch = tid + 256 * j;
      int r = ch >> 4, cl = ch & 15;
      s16x8 v = *(const s16x8*)(ktp + ch * 8);
      int sw = (cl & 8) | ((cl ^ (r & 7)) & 7);
      *(s16x8*)((char*)Ks + r * 256 + sw * 16) = v;
    }
    // stage Vt tile: [128][64]
#pragma unroll
    for (int j = 0; j < 4; j++) {
      int ch = tid + 256 * j;
      int r = ch >> 3, p = ch & 7;
      s16x8 v = *(const s16x8*)(Vp + (size_t)r * 2048 + s0 + p * 8);
      int sw = p ^ (r & 7);
      *(s16x8*)((char*)Vs + r * 128 + sw * 16) = v;
    }
    __syncthreads();

    if (s0 <= qr0 + 31) {
      // QK^T
      f32x4 sc[2][4];
#pragma unroll
      for (int mi = 0; mi < 2; mi++)
#pragma unroll
        for (int kb = 0; kb < 4; kb++) sc[mi][kb] = f32x4{0.f, 0.f, 0.f, 0.f};
#pragma unroll
      for (int kb = 0; kb < 4; kb++) {
        int r = kb * 16 + l15;
#pragma unroll
        for (int ks = 0; ks < 4; ks++) {
          int c = ks * 4 + l4;
          int sw = (c & 8) | ((c ^ (r & 7)) & 7);
          s16x8 kf = *(const s16x8*)((char*)Ks + r * 256 + sw * 16);
          sc[0][kb] = mfma_bf16(qf[0][ks], kf, sc[0][kb]);
          sc[1][kb] = mfma_bf16(qf[1][ks], kf, sc[1][kb]);
        }
      }
      bool needmask = (s0 + 63) > qr0;
#pragma unroll
      for (int mi = 0; mi < 2; mi++) {
        if (needmask) {
#pragma unroll
          for (int kb = 0; kb < 4; kb++) {
            int kg = s0 + kb * 16 + l15;
#pragma unroll
            for (int pr = 0; pr < 4; pr++) {
              int qg = qr0 + mi * 16 + l4 * 4 + pr;
              if (kg > qg) sc[mi][kb][pr] = -1e30f;
            }
          }
        }
        float rm[4];
#pragma unroll
        for (int pr = 0; pr < 4; pr++)
          rm[pr] = fmaxf(fmaxf(sc[mi][0][pr], sc[mi][1][pr]),
                         fmaxf(sc[mi][2][pr], sc[mi][3][pr]));
#pragma unroll
        for (int xm = 1; xm <= 8; xm <<= 1)
#pragma unroll
          for (int pr = 0; pr < 4; pr++)
            rm[pr] = fmaxf(rm[pr], __shfl_xor(rm[pr], xm, 64));
        float fac[4];
#pragma unroll
        for (int pr = 0; pr < 4; pr++) {
          float nm = fmaxf(m[mi][pr], rm[pr]);
          fac[pr] = __builtin_amdgcn_exp2f((m[mi][pr] - nm) * CSOFT);
          m[mi][pr] = nm;
          lsum[mi][pr] *= fac[pr];
        }
        float rs[4] = {0.f, 0.f, 0.f, 0.f};
#pragma unroll
        for (int kb = 0; kb < 4; kb++)
#pragma unroll
          for (int pr = 0; pr < 4; pr++) {
            float p = __builtin_amdgcn_exp2f((sc[mi][kb][pr] - m[mi][pr]) * CSOFT);
            sc[mi][kb][pr] = p;
            rs[pr] += p;
          }
#pragma unroll
        for (int xm = 1; xm <= 8; xm <<= 1)
#pragma unroll
          for (int pr = 0; pr < 4; pr++) rs[pr] += __shfl_xor(rs[pr], xm, 64);
#pragma unroll
        for (int pr = 0; pr < 4; pr++) lsum[mi][pr] += rs[pr];
#pragma unroll
        for (int nb = 0; nb < 8; nb++)
#pragma unroll
          for (int pr = 0; pr < 4; pr++) o[mi][nb][pr] *= fac[pr];
        // write P (bf16) to per-wave swizzled LDS
        char* pb = (char*)(&Ps[wid][0]);
#pragma unroll
        for (int kb = 0; kb < 4; kb++) {
          int col = kb * 16 + l15;
#pragma unroll
          for (int pr = 0; pr < 4; pr++) {
            int row = mi * 16 + l4 * 4 + pr;
            *(unsigned short*)(pb + row * 128 + (((col >> 3) ^ (row & 7)) * 16) +
                               (col & 7) * 2) = f2bf(sc[mi][kb][pr]);
          }
        }
      }
      // PV
      char* pb = (char*)(&Ps[wid][0]);
#pragma unroll
      for (int ks = 0; ks < 2; ks++) {
        s16x8 pa[2];
#pragma unroll
        for (int mi = 0; mi < 2; mi++) {
          int row = mi * 16 + l15;
          int c = ks * 4 + l4;
          pa[mi] = *(const s16x8*)(pb + row * 128 + ((c ^ (row & 7)) * 16));
        }
#pragma unroll
        for (int nb = 0; nb < 8; nb++) {
          int r = nb * 16 + l15;
          int c = ks * 4 + l4;
          s16x8 vf = *(const s16x8*)((char*)Vs + r * 128 + ((c ^ (r & 7)) * 16));
          o[0][nb] = mfma_bf16(pa[0], vf, o[0][nb]);
          o[1][nb] = mfma_bf16(pa[1], vf, o[1][nb]);
        }
      }
    }
    __syncthreads();
  }

  // normalize + store AO token-major [n][h*128+col]
#pragma unroll
  for (int mi = 0; mi < 2; mi++) {
    float inv[4];
#pragma unroll
    for (int pr = 0; pr < 4; pr++) inv[pr] = 1.f / lsum[mi][pr];
#pragma unroll
    for (int nb = 0; nb < 8; nb++) {
      int col = h * 128 + nb * 16 + l15;
#pragma unroll
      for (int pr = 0; pr < 4; pr++) {
        int q = qr0 + mi * 16 + l4 * 4 + pr;
        AO[(size_t)(q * 2 + b) * 4096 + col] = f2bf(o[mi][nb][pr] * inv[pr]);
      }
    }
  }
}

// ---------------- launch ----------------
extern "C" void kernel_launch(void* const* d_in, const int* in_sizes, int n_in,
                              void* d_out, int out_size, void* d_ws, size_t ws_size,
                              hipStream_t stream) {
  const float* x = (const float*)d_in[0];
  const float* cosT = (const float*)d_in[2];
  const float* sinT = (const float*)d_in[3];
  const float* wq = (const float*)d_in[4];
  const float* wk = (const float*)d_in[5];
  const float* wv = (const float*)d_in[6];
  const float* wo = (const float*)d_in[7];
  float* out = (float*)d_out;

  char* ws = (char*)d_ws;
  unsigned short* xb = (unsigned short*)(ws);
  unsigned short* Qa = (unsigned short*)(ws + 33554432ull);
  unsigned short* Ka = (unsigned short*)(ws + 67108864ull);
  unsigned short* Vt = (unsigned short*)(ws + 75497472ull);
  unsigned short* AO = (unsigned short*)(ws + 83886080ull);
  unsigned short* wqb = (unsigned short*)(ws + 117440512ull);
  unsigned short* wkb = (unsigned short*)(ws + 150994944ull);
  unsigned short* wvb = (unsigned short*)(ws + 159383552ull);
  unsigned short* wob = (unsigned short*)(ws + 167772160ull);
  bool wcvt = ws_size >= 201326592ull;

  cvt_bf16<<<8192, 256, 0, stream>>>(x, xb, 2097152);
  if (wcvt) {
    cvt_bf16<<<8192, 256, 0, stream>>>(wq, wqb, 2097152);
    cvt_bf16<<<2048, 256, 0, stream>>>(wk, wkb, 524288);
    cvt_bf16<<<2048, 256, 0, stream>>>(wv, wvb, 524288);
    cvt_bf16<<<8192, 256, 0, stream>>>(wo, wob, 2097152);
    gemm_bt<0, 4096, false><<<1024, 256, 0, stream>>>(xb, nullptr, wqb, Qa, cosT, sinT);
    gemm_bt<1, 1024, false><<<256, 256, 0, stream>>>(xb, nullptr, wkb, Ka, cosT, sinT);
    gemm_bt<2, 1024, false><<<256, 256, 0, stream>>>(xb, nullptr, wvb, Vt, cosT, sinT);
  } else {
    gemm_bt<0, 4096, true><<<1024, 256, 0, stream>>>(xb, wq, nullptr, Qa, cosT, sinT);
    gemm_bt<1, 1024, true><<<256, 256, 0, stream>>>(xb, wk, nullptr, Ka, cosT, sinT);
    gemm_bt<2, 1024, true><<<256, 256, 0, stream>>>(xb, wv, nullptr, Vt, cosT, sinT);
  }
  attn_fwd<<<1024, 256, 0, stream>>>(Qa, Ka, Vt, AO);
  if (wcvt) {
    gemm_bt<3, 4096, false><<<1024, 256, 0, stream>>>(AO, nullptr, wob, out, cosT, sinT);
  } else {
    gemm_bt<3, 4096, true><<<1024, 256, 0, stream>>>(AO, wo, nullptr, out, cosT, sinT);
  }
}

// Round 2
// 670.303 us; speedup vs baseline: 1.1693x; 1.1693x over previous
//
#include <hip/hip_runtime.h>

typedef __attribute__((ext_vector_type(8))) short s16x8;
typedef __attribute__((ext_vector_type(8))) __bf16 bf16x8;
typedef __attribute__((ext_vector_type(4))) float f32x4;

#define S_LEN 2048
#define KDIM  4096
// softmax scale * log2(e): (1/sqrt(128)) * 1.4426950408889634
#define CSOFT 0.12751743f

__device__ __forceinline__ unsigned short f2bf(float f) {
  unsigned u = __builtin_bit_cast(unsigned, f);
  u += 0x7fffu + ((u >> 16) & 1u);
  return (unsigned short)(u >> 16);
}

__device__ __forceinline__ f32x4 mfma_bf16(s16x8 a, s16x8 b, f32x4 c) {
  return __builtin_amdgcn_mfma_f32_16x16x32_bf16(
      __builtin_bit_cast(bf16x8, a), __builtin_bit_cast(bf16x8, b), c, 0, 0, 0);
}

// async global->LDS, 16B per lane. lds ptr must be wave-uniform; g is per-lane.
__device__ __forceinline__ void gload_lds16(const unsigned short* g, void* l) {
  __builtin_amdgcn_global_load_lds(
      (const __attribute__((address_space(1))) void*)g,
      (__attribute__((address_space(3))) void*)l, 16, 0, 0);
}

// ---------------- fp32 -> bf16 convert ----------------
__global__ void cvt_bf16(const float* __restrict__ in,
                         unsigned short* __restrict__ out, int n8) {
  int i = blockIdx.x * 256 + threadIdx.x;
  if (i >= n8) return;
  const float* p = in + (size_t)i * 8;
  f32x4 a = *(const f32x4*)(p);
  f32x4 b = *(const f32x4*)(p + 4);
  s16x8 v;
  v[0] = (short)f2bf(a[0]); v[1] = (short)f2bf(a[1]);
  v[2] = (short)f2bf(a[2]); v[3] = (short)f2bf(a[3]);
  v[4] = (short)f2bf(b[0]); v[5] = (short)f2bf(b[1]);
  v[6] = (short)f2bf(b[2]); v[7] = (short)f2bf(b[3]);
  *(s16x8*)(out + (size_t)i * 8) = v;
}

// ---------------- GEMM: C[M,N] = A[M,K] @ B[N,K]^T, bf16 in, epilogues ----
// EPI: 0 = Q (rope, store [b][32+h][s][hd]), 1 = K (rope, store [b][8][s][hd]),
//      2 = V (store transposed [b][8][hd][s]),  3 = O (store fp32 token-major)
// LDS layout: [row][chunk], chunk' = chunk ^ ((row>>1)&3)  (XOR involution).
// A is staged via global_load_lds with pre-swizzled SOURCE (linear dest);
// reads use the same swizzle -> conflict-free ds_read_b128.
template <int EPI, int N, bool B_FP32>
__global__ __launch_bounds__(256, 2)
void gemm_bt(const unsigned short* __restrict__ A,
             const float* __restrict__ Bw32,
             const unsigned short* __restrict__ Bw16,
             void* __restrict__ Out,
             const float* __restrict__ cosT,
             const float* __restrict__ sinT) {
  const int K = KDIM;
  const int tid = threadIdx.x;
  const int lane = tid & 63, wid = tid >> 6;
  const int l15 = lane & 15, l4 = lane >> 4;
  const int nct = N / 128;
  const int ct = blockIdx.x % nct, rt = blockIdx.x / nct;
  const int row0 = rt * 128, col0 = ct * 128;
  const int wr = wid >> 1, wc = wid & 1;

  __shared__ __align__(16) unsigned short As[128 * 32];
  __shared__ __align__(16) unsigned short Bs[128 * 32];

  f32x4 acc[4][4];
#pragma unroll
  for (int i = 0; i < 4; i++)
#pragma unroll
    for (int j = 0; j < 4; j++) acc[i][j] = f32x4{0.f, 0.f, 0.f, 0.f};

  for (int kt = 0; kt < K; kt += 32) {
    // stage A via global_load_lds: 8 instrs of 1KB, 2 per wave
#pragma unroll
    for (int i = 0; i < 2; i++) {
      int j = wid * 2 + i;
      int ch = j * 64 + lane;
      int r = ch >> 2, c = ch & 3;
      int sc = c ^ ((r >> 1) & 3);
      gload_lds16(A + (size_t)(row0 + r) * K + kt + sc * 8, (char*)As + j * 1024);
    }
    if (B_FP32) {
      // fallback: reg-stage + convert
#pragma unroll
      for (int j = 0; j < 2; j++) {
        int ch = tid + 256 * j;
        int r = ch >> 2, c = ch & 3;
        const float* src = Bw32 + (size_t)(col0 + r) * K + kt + c * 8;
        f32x4 f0 = *(const f32x4*)(src);
        f32x4 f1 = *(const f32x4*)(src + 4);
        s16x8 v;
        v[0] = (short)f2bf(f0[0]); v[1] = (short)f2bf(f0[1]);
        v[2] = (short)f2bf(f0[2]); v[3] = (short)f2bf(f0[3]);
        v[4] = (short)f2bf(f1[0]); v[5] = (short)f2bf(f1[1]);
        v[6] = (short)f2bf(f1[2]); v[7] = (short)f2bf(f1[3]);
        int sw = c ^ ((r >> 1) & 3);
        *(s16x8*)((char*)Bs + r * 64 + sw * 16) = v;
      }
    } else {
#pragma unroll
      for (int i = 0; i < 2; i++) {
        int j = wid * 2 + i;
        int ch = j * 64 + lane;
        int r = ch >> 2, c = ch & 3;
        int sc = c ^ ((r >> 1) & 3);
        gload_lds16(Bw16 + (size_t)(col0 + r) * K + kt + sc * 8, (char*)Bs + j * 1024);
      }
    }
    __syncthreads();

    s16x8 af[4], bfr[4];
#pragma unroll
    for (int mi = 0; mi < 4; mi++) {
      int r = wr * 64 + mi * 16 + l15;
      int sw = l4 ^ ((r >> 1) & 3);
      af[mi] = *(const s16x8*)((char*)As + r * 64 + sw * 16);
    }
#pragma unroll
    for (int ni = 0; ni < 4; ni++) {
      int r = wc * 64 + ni * 16 + l15;
      int sw = l4 ^ ((r >> 1) & 3);
      bfr[ni] = *(const s16x8*)((char*)Bs + r * 64 + sw * 16);
    }
#pragma unroll
    for (int mi = 0; mi < 4; mi++)
#pragma unroll
      for (int ni = 0; ni < 4; ni++)
        acc[mi][ni] = mfma_bf16(af[mi], bfr[ni], acc[mi][ni]);
    __syncthreads();
  }

  // epilogue
#pragma unroll
  for (int mi = 0; mi < 4; mi++) {
#pragma unroll
    for (int ni = 0; ni < 4; ni++) {
      f32x4 v = acc[mi][ni];
      int rowb = row0 + wr * 64 + mi * 16 + l4 * 4;  // token base (4 rows)
      int col = col0 + wc * 64 + ni * 16 + l15;
      if (EPI == 3) {
        float* o = (float*)Out;
#pragma unroll
        for (int r = 0; r < 4; r++) o[(size_t)(rowb + r) * 4096 + col] = v[r];
      } else {
        if (EPI != 2) {  // RoPE for Q,K
          float vp[4];
#pragma unroll
          for (int r = 0; r < 4; r++) vp[r] = __shfl_xor(v[r], 1, 64);
          bool odd = lane & 1;
          int fi = (col & 127) >> 1;
#pragma unroll
          for (int r = 0; r < 4; r++) {
            int n = rowb + r, s = n >> 1;
            float c = cosT[s * 64 + fi], sn = sinT[s * 64 + fi];
            v[r] = odd ? (vp[r] * sn + v[r] * c) : (v[r] * c - vp[r] * sn);
          }
        }
        unsigned short* o = (unsigned short*)Out;
        int hh = col >> 7, hd = col & 127;
#pragma unroll
        for (int r = 0; r < 4; r++) {
          int n = rowb + r, s = n >> 1, b = n & 1;
          size_t idx;
          if (EPI == 0)      idx = ((size_t)(b * 32 + hh) * 2048 + s) * 128 + hd;
          else if (EPI == 1) idx = ((size_t)(b * 8 + hh) * 2048 + s) * 128 + hd;
          else               idx = ((size_t)(b * 8 + hh) * 128 + hd) * 2048 + s;
          o[idx] = f2bf(v[r]);
        }
      }
    }
  }
}

// ---------------- Flash attention (causal, GQA) ----------------
// grid: 8 pid x 32 heads x 2 batch = 512 blocks. block: 256 threads.
// Each block processes qt = 7-pid then qt = 8+pid -> uniform 34 KV-tile units.
__global__ __launch_bounds__(256, 2)
void attn_fwd(const unsigned short* __restrict__ Qa,
              const unsigned short* __restrict__ Ka,
              const unsigned short* __restrict__ Vt,
              unsigned short* __restrict__ AO) {
  int bid = blockIdx.x;
  int pid = bid & 7;
  int h = (bid >> 3) & 31;
  int b = bid >> 8;
  int kvh = h >> 2;
  int tid = threadIdx.x, lane = tid & 63, wid = tid >> 6;
  int l15 = lane & 15, l4 = lane >> 4;

  __shared__ __align__(16) unsigned short Ks[64 * 128];   // [kv][hd] swizzled
  __shared__ __align__(16) unsigned short Vs[128 * 64];   // [hd][kv] swizzled
  __shared__ __align__(16) unsigned short Ps[4][32 * 64]; // per-wave P

  const unsigned short* Qp = Qa + ((size_t)(b * 32 + h) * 2048) * 128;
  const unsigned short* Kp = Ka + ((size_t)(b * 8 + kvh) * 2048) * 128;
  const unsigned short* Vp = Vt + ((size_t)(b * 8 + kvh) * 128) * 2048;

  for (int half = 0; half < 2; half++) {
    int qt = half == 0 ? (7 - pid) : (8 + pid);
    int q0 = qt * 128, qr0 = q0 + wid * 32;

    s16x8 qf[2][4];
#pragma unroll
    for (int mi = 0; mi < 2; mi++)
#pragma unroll
      for (int ks = 0; ks < 4; ks++)
        qf[mi][ks] = *(const s16x8*)(Qp + (size_t)(qr0 + mi * 16 + l15) * 128 +
                                     ks * 32 + l4 * 8);

    f32x4 o[2][8];
#pragma unroll
    for (int mi = 0; mi < 2; mi++)
#pragma unroll
      for (int nb = 0; nb < 8; nb++) o[mi][nb] = f32x4{0.f, 0.f, 0.f, 0.f};
    float m[2][4], lsum[2][4];
#pragma unroll
    for (int mi = 0; mi < 2; mi++)
#pragma unroll
      for (int pr = 0; pr < 4; pr++) { m[mi][pr] = -1e30f; lsum[mi][pr] = 0.f; }

    int nt = q0 / 64 + 2;
    for (int t = 0; t < nt; t++) {
      int s0 = t * 64;
      const unsigned short* ktp = Kp + (size_t)s0 * 128;
      // stage K (16KB) + V (16KB) via global_load_lds, pre-swizzled source
#pragma unroll
      for (int i = 0; i < 4; i++) {
        int j = wid * 4 + i;
        int ch = j * 64 + lane;
        {
          int r = ch >> 4, cl = ch & 15;
          int sc = (cl & 8) | ((cl ^ (r & 7)) & 7);
          gload_lds16(ktp + r * 128 + sc * 8, (char*)Ks + j * 1024);
        }
        {
          int r = ch >> 3, p = ch & 7;
          int sc = p ^ (r & 7);
          gload_lds16(Vp + (size_t)r * 2048 + s0 + sc * 8, (char*)Vs + j * 1024);
        }
      }
      __syncthreads();

      if (s0 <= qr0 + 31) {
        // QK^T
        f32x4 sc[2][4];
#pragma unroll
        for (int mi = 0; mi < 2; mi++)
#pragma unroll
          for (int kb = 0; kb < 4; kb++) sc[mi][kb] = f32x4{0.f, 0.f, 0.f, 0.f};
#pragma unroll
        for (int kb = 0; kb < 4; kb++) {
          int r = kb * 16 + l15;
#pragma unroll
          for (int ks = 0; ks < 4; ks++) {
            int c = ks * 4 + l4;
            int sw = (c & 8) | ((c ^ (r & 7)) & 7);
            s16x8 kf = *(const s16x8*)((char*)Ks + r * 256 + sw * 16);
            sc[0][kb] = mfma_bf16(qf[0][ks], kf, sc[0][kb]);
            sc[1][kb] = mfma_bf16(qf[1][ks], kf, sc[1][kb]);
          }
        }
        bool needmask = (s0 + 63) > qr0;
#pragma unroll
        for (int mi = 0; mi < 2; mi++) {
          if (needmask) {
#pragma unroll
            for (int kb = 0; kb < 4; kb++) {
              int kg = s0 + kb * 16 + l15;
#pragma unroll
              for (int pr = 0; pr < 4; pr++) {
                int qg = qr0 + mi * 16 + l4 * 4 + pr;
                if (kg > qg) sc[mi][kb][pr] = -1e30f;
              }
            }
          }
          float rm[4];
#pragma unroll
          for (int pr = 0; pr < 4; pr++)
            rm[pr] = fmaxf(fmaxf(sc[mi][0][pr], sc[mi][1][pr]),
                           fmaxf(sc[mi][2][pr], sc[mi][3][pr]));
#pragma unroll
          for (int xm = 1; xm <= 8; xm <<= 1)
#pragma unroll
            for (int pr = 0; pr < 4; pr++)
              rm[pr] = fmaxf(rm[pr], __shfl_xor(rm[pr], xm, 64));
          // T13 defer-max: skip rescale when growth small (p bounded by 2^8)
          bool grow = false;
#pragma unroll
          for (int pr = 0; pr < 4; pr++)
            grow = grow || ((rm[pr] - m[mi][pr]) * CSOFT > 8.f);
          if (__any(grow)) {
            float fac[4];
#pragma unroll
            for (int pr = 0; pr < 4; pr++) {
              float nm = fmaxf(m[mi][pr], rm[pr]);
              fac[pr] = __builtin_amdgcn_exp2f((m[mi][pr] - nm) * CSOFT);
              m[mi][pr] = nm;
              lsum[mi][pr] *= fac[pr];
            }
#pragma unroll
            for (int nb = 0; nb < 8; nb++)
#pragma unroll
              for (int pr = 0; pr < 4; pr++) o[mi][nb][pr] *= fac[pr];
          }
          float rs[4] = {0.f, 0.f, 0.f, 0.f};
#pragma unroll
          for (int kb = 0; kb < 4; kb++)
#pragma unroll
            for (int pr = 0; pr < 4; pr++) {
              float p = __builtin_amdgcn_exp2f((sc[mi][kb][pr] - m[mi][pr]) * CSOFT);
              sc[mi][kb][pr] = p;
              rs[pr] += p;
            }
#pragma unroll
          for (int xm = 1; xm <= 8; xm <<= 1)
#pragma unroll
            for (int pr = 0; pr < 4; pr++) rs[pr] += __shfl_xor(rs[pr], xm, 64);
#pragma unroll
          for (int pr = 0; pr < 4; pr++) lsum[mi][pr] += rs[pr];
          // write P (bf16) to per-wave swizzled LDS
          char* pb = (char*)(&Ps[wid][0]);
#pragma unroll
          for (int kb = 0; kb < 4; kb++) {
            int col = kb * 16 + l15;
#pragma unroll
            for (int pr = 0; pr < 4; pr++) {
              int row = mi * 16 + l4 * 4 + pr;
              *(unsigned short*)(pb + row * 128 + (((col >> 3) ^ (row & 7)) * 16) +
                                 (col & 7) * 2) = f2bf(sc[mi][kb][pr]);
            }
          }
        }
        // PV
        char* pb = (char*)(&Ps[wid][0]);
#pragma unroll
        for (int ks = 0; ks < 2; ks++) {
          s16x8 pa[2];
#pragma unroll
          for (int mi = 0; mi < 2; mi++) {
            int row = mi * 16 + l15;
            int c = ks * 4 + l4;
            pa[mi] = *(const s16x8*)(pb + row * 128 + ((c ^ (row & 7)) * 16));
          }
#pragma unroll
          for (int nb = 0; nb < 8; nb++) {
            int r = nb * 16 + l15;
            int c = ks * 4 + l4;
            s16x8 vf = *(const s16x8*)((char*)Vs + r * 128 + ((c ^ (r & 7)) * 16));
            o[0][nb] = mfma_bf16(pa[0], vf, o[0][nb]);
            o[1][nb] = mfma_bf16(pa[1], vf, o[1][nb]);
          }
        }
      }
      __syncthreads();
    }

    // normalize + store AO token-major [n][h*128+col]
#pragma unroll
    for (int mi = 0; mi < 2; mi++) {
      float inv[4];
#pragma unroll
      for (int pr = 0; pr < 4; pr++) inv[pr] = 1.f / lsum[mi][pr];
#pragma unroll
      for (int nb = 0; nb < 8; nb++) {
        int col = h * 128 + nb * 16 + l15;
#pragma unroll
        for (int pr = 0; pr < 4; pr++) {
          int q = qr0 + mi * 16 + l4 * 4 + pr;
          AO[(size_t)(q * 2 + b) * 4096 + col] = f2bf(o[mi][nb][pr] * inv[pr]);
        }
      }
    }
  }
}

// ---------------- launch ----------------
extern "C" void kernel_launch(void* const* d_in, const int* in_sizes, int n_in,
                              void* d_out, int out_size, void* d_ws, size_t ws_size,
                              hipStream_t stream) {
  const float* x = (const float*)d_in[0];
  const float* cosT = (const float*)d_in[2];
  const float* sinT = (const float*)d_in[3];
  const float* wq = (const float*)d_in[4];
  const float* wk = (const float*)d_in[5];
  const float* wv = (const float*)d_in[6];
  const float* wo = (const float*)d_in[7];
  float* out = (float*)d_out;

  char* ws = (char*)d_ws;
  unsigned short* xb = (unsigned short*)(ws);
  unsigned short* Qa = (unsigned short*)(ws + 33554432ull);
  unsigned short* Ka = (unsigned short*)(ws + 67108864ull);
  unsigned short* Vt = (unsigned short*)(ws + 75497472ull);
  unsigned short* AO = (unsigned short*)(ws + 83886080ull);
  unsigned short* wqb = (unsigned short*)(ws + 117440512ull);
  unsigned short* wkb = (unsigned short*)(ws + 150994944ull);
  unsigned short* wvb = (unsigned short*)(ws + 159383552ull);
  unsigned short* wob = (unsigned short*)(ws + 167772160ull);
  bool wcvt = ws_size >= 201326592ull;

  cvt_bf16<<<8192, 256, 0, stream>>>(x, xb, 2097152);
  if (wcvt) {
    cvt_bf16<<<8192, 256, 0, stream>>>(wq, wqb, 2097152);
    cvt_bf16<<<2048, 256, 0, stream>>>(wk, wkb, 524288);
    cvt_bf16<<<2048, 256, 0, stream>>>(wv, wvb, 524288);
    cvt_bf16<<<8192, 256, 0, stream>>>(wo, wob, 2097152);
    gemm_bt<0, 4096, false><<<1024, 256, 0, stream>>>(xb, nullptr, wqb, Qa, cosT, sinT);
    gemm_bt<1, 1024, false><<<256, 256, 0, stream>>>(xb, nullptr, wkb, Ka, cosT, sinT);
    gemm_bt<2, 1024, false><<<256, 256, 0, stream>>>(xb, nullptr, wvb, Vt, cosT, sinT);
  } else {
    gemm_bt<0, 4096, true><<<1024, 256, 0, stream>>>(xb, wq, nullptr, Qa, cosT, sinT);
    gemm_bt<1, 1024, true><<<256, 256, 0, stream>>>(xb, wk, nullptr, Ka, cosT, sinT);
    gemm_bt<2, 1024, true><<<256, 256, 0, stream>>>(xb, wv, nullptr, Vt, cosT, sinT);
  }
  attn_fwd<<<512, 256, 0, stream>>>(Qa, Ka, Vt, AO);
  if (wcvt) {
    gemm_bt<3, 4096, false><<<1024, 256, 0, stream>>>(AO, nullptr, wob, out, cosT, sinT);
  } else {
    gemm_bt<3, 4096, true><<<1024, 256, 0, stream>>>(AO, wo, nullptr, out, cosT, sinT);
  }
}

// Round 3
// 640.921 us; speedup vs baseline: 1.2229x; 1.0458x over previous
//
#include <hip/hip_runtime.h>

typedef __attribute__((ext_vector_type(8))) short s16x8;
typedef __attribute__((ext_vector_type(8))) __bf16 bf16x8;
typedef __attribute__((ext_vector_type(4))) float f32x4;

#define S_LEN 2048
#define KDIM  4096
// softmax scale * log2(e): (1/sqrt(128)) * 1.4426950408889634
#define CSOFT 0.12751743f

__device__ __forceinline__ unsigned short f2bf(float f) {
  unsigned u = __builtin_bit_cast(unsigned, f);
  u += 0x7fffu + ((u >> 16) & 1u);
  return (unsigned short)(u >> 16);
}

__device__ __forceinline__ f32x4 mfma_bf16(s16x8 a, s16x8 b, f32x4 c) {
  return __builtin_amdgcn_mfma_f32_16x16x32_bf16(
      __builtin_bit_cast(bf16x8, a), __builtin_bit_cast(bf16x8, b), c, 0, 0, 0);
}

// async global->LDS, 16B per lane. lds ptr must be wave-uniform; g is per-lane.
__device__ __forceinline__ void gload_lds16(const unsigned short* g, void* l) {
  __builtin_amdgcn_global_load_lds(
      (const __attribute__((address_space(1))) void*)g,
      (__attribute__((address_space(3))) void*)l, 16, 0, 0);
}

// ---------------- fp32 -> bf16 convert ----------------
__global__ void cvt_bf16(const float* __restrict__ in,
                         unsigned short* __restrict__ out, int n8) {
  int i = blockIdx.x * 256 + threadIdx.x;
  if (i >= n8) return;
  const float* p = in + (size_t)i * 8;
  f32x4 a = *(const f32x4*)(p);
  f32x4 b = *(const f32x4*)(p + 4);
  s16x8 v;
  v[0] = (short)f2bf(a[0]); v[1] = (short)f2bf(a[1]);
  v[2] = (short)f2bf(a[2]); v[3] = (short)f2bf(a[3]);
  v[4] = (short)f2bf(b[0]); v[5] = (short)f2bf(b[1]);
  v[6] = (short)f2bf(b[2]); v[7] = (short)f2bf(b[3]);
  *(s16x8*)(out + (size_t)i * 8) = v;
}

// ============ 256x256 BK=32 8-wave 4-phase double-buffered GEMM ============
// C[M=4096, N=4096] = A @ B^T (both bf16 row-major [*, K=4096]).
// EPI: 0 = Q (rope, store [b][h][s][hd]),  3 = O (store fp32 token-major)
// Wave grid 1x8: wave wid owns rows rt*256..+255, cols ct*256 + wid*32..+31.
// LDS per K-tile: A 256x32, B 256x32 bf16 (16KB each), double-buffered = 64KB.
// Layout: 2 source rows packed per 128B line; slot s = ((r&1)*4 + c) ^ (L&7)
//   (L = line index). Staged linearly by gload_lds with pre-swizzled source.
// Per tile: 4 phases x 8 MFMA; stage order B0,B1,A0,A1 (one half per phase);
//   vmcnt(1) at ph1-end (cur.A1 ready for ph2 reads) and ph4-end (next tile's
//   B0,B1,A0 ready; next.A1 stays in flight). Never vmcnt(0) in main loop.
template <int EPI>
__global__ __launch_bounds__(512, 2)
void gemm256(const unsigned short* __restrict__ A,
             const unsigned short* __restrict__ B,
             void* __restrict__ Out,
             const float* __restrict__ cosT,
             const float* __restrict__ sinT) {
  const int K = KDIM;
  const int NT = KDIM / 32;
  __shared__ __align__(16) unsigned short As[2][256 * 32];
  __shared__ __align__(16) unsigned short Bs[2][256 * 32];

  const int tid = threadIdx.x;
  const int lane = tid & 63, wid = tid >> 6;
  const int l15 = lane & 15, l4 = lane >> 4;
  const int wc = wid;

  // XCD-aware swizzle (256 blocks, 8 XCDs, 32 per XCD)
  int bid = blockIdx.x;
  int wg = (bid & 7) * 32 + (bid >> 3);
  const int rt = wg >> 4, ct = wg & 15;
  const int row0 = rt * 256, col0 = ct * 256;

  // staging source (pre-swizzled): chunk ch -> line L, slot s; source
  // (r, c): u = s ^ (L&7); r = 2L + (u>>2); c = (u&3)*8
  {}
  const int ch = wid * 64 + lane;
  const int sL = ch >> 3, ss = ch & 7;
  const int su = ss ^ (sL & 7);
  const int sr = 2 * sL + (su >> 2);
  const int sc = (su & 3) * 8;
  const unsigned short* Asrc = A + (size_t)(row0 + sr) * K + sc;
  const unsigned short* Bsrc = B + (size_t)(col0 + sr) * K + sc;

  // read-side fragment offset (byte), frag (mi): base + mi*1024 + rdoff
  const int rdoff = (l15 >> 1) * 128 +
                    (((((l15 & 1) << 2) | l4) ^ ((l15 >> 1) & 7)) << 4);

  f32x4 acc[16][2];
#pragma unroll
  for (int i = 0; i < 16; i++) {
    acc[i][0] = f32x4{0.f, 0.f, 0.f, 0.f};
    acc[i][1] = f32x4{0.f, 0.f, 0.f, 0.f};
  }

  auto stage = [&](int buf, int half, bool isB, int kt) {
    const unsigned short* src =
        (isB ? Bsrc : Asrc) + (size_t)half * 128 * K + kt;
    char* dst = (char*)(isB ? &Bs[buf][0] : &As[buf][0]) + half * 8192 +
                wid * 1024;
    gload_lds16(src, dst);
  };

  // prologue: stage tile 0 fully; order B0,B1,A0,A1; wait all but A1
  stage(0, 0, true, 0);
  stage(0, 1, true, 0);
  stage(0, 0, false, 0);
  stage(0, 1, false, 0);
  asm volatile("s_waitcnt vmcnt(1)" ::: "memory");
  __builtin_amdgcn_s_barrier();
  __builtin_amdgcn_sched_barrier(0);

  for (int t = 0; t < NT; ++t) {
    const int cur = t & 1, nxt = cur ^ 1;
    const int ktn = (t + 1) * 32;
    const bool pf = (t + 1) < NT;
    const char* Ab = (const char*)&As[cur][0];
    const char* Bb = (const char*)&Bs[cur][0];

    // ---- phase 1: read B frags + A0 frags; stage next.B0; MFMA mi0-3 ----
    s16x8 bf0 = *(const s16x8*)(Bb + wc * 2048 + rdoff);
    s16x8 bf1 = *(const s16x8*)(Bb + wc * 2048 + 1024 + rdoff);
    s16x8 afA[8];
#pragma unroll
    for (int mi = 0; mi < 8; mi++)
      afA[mi] = *(const s16x8*)(Ab + mi * 1024 + rdoff);
    if (pf) stage(nxt, 0, true, ktn);
    __builtin_amdgcn_s_barrier();
    __builtin_amdgcn_sched_barrier(0);
    __builtin_amdgcn_s_setprio(1);
#pragma unroll
    for (int mi = 0; mi < 4; mi++) {
      acc[mi][0] = mfma_bf16(afA[mi], bf0, acc[mi][0]);
      acc[mi][1] = mfma_bf16(afA[mi], bf1, acc[mi][1]);
    }
    __builtin_amdgcn_s_setprio(0);
    if (pf) { asm volatile("s_waitcnt vmcnt(1)" ::: "memory"); }
    else    { asm volatile("s_waitcnt vmcnt(0)" ::: "memory"); }
    __builtin_amdgcn_s_barrier();
    __builtin_amdgcn_sched_barrier(0);

    // ---- phase 2: read A1 frags; stage next.B1; MFMA mi4-7 ----
    s16x8 afB[8];
#pragma unroll
    for (int mi = 0; mi < 8; mi++)
      afB[mi] = *(const s16x8*)(Ab + 8192 + mi * 1024 + rdoff);
    if (pf) stage(nxt, 1, true, ktn);
    __builtin_amdgcn_s_barrier();
    __builtin_amdgcn_sched_barrier(0);
    __builtin_amdgcn_s_setprio(1);
#pragma unroll
    for (int mi = 4; mi < 8; mi++) {
      acc[mi][0] = mfma_bf16(afA[mi], bf0, acc[mi][0]);
      acc[mi][1] = mfma_bf16(afA[mi], bf1, acc[mi][1]);
    }
    __builtin_amdgcn_s_setprio(0);
    __builtin_amdgcn_s_barrier();
    __builtin_amdgcn_sched_barrier(0);

    // ---- phase 3: stage next.A0; MFMA mi8-11 ----
    if (pf) stage(nxt, 0, false, ktn);
    __builtin_amdgcn_s_barrier();
    __builtin_amdgcn_sched_barrier(0);
    __builtin_amdgcn_s_setprio(1);
#pragma unroll
    for (int mi = 0; mi < 4; mi++) {
      acc[8 + mi][0] = mfma_bf16(afB[mi], bf0, acc[8 + mi][0]);
      acc[8 + mi][1] = mfma_bf16(afB[mi], bf1, acc[8 + mi][1]);
    }
    __builtin_amdgcn_s_setprio(0);
    __builtin_amdgcn_s_barrier();
    __builtin_amdgcn_sched_barrier(0);

    // ---- phase 4: stage next.A1; MFMA mi12-15; boundary wait ----
    if (pf) stage(nxt, 1, false, ktn);
    __builtin_amdgcn_s_barrier();
    __builtin_amdgcn_sched_barrier(0);
    __builtin_amdgcn_s_setprio(1);
#pragma unroll
    for (int mi = 4; mi < 8; mi++) {
      acc[8 + mi][0] = mfma_bf16(afB[mi], bf0, acc[8 + mi][0]);
      acc[8 + mi][1] = mfma_bf16(afB[mi], bf1, acc[8 + mi][1]);
    }
    __builtin_amdgcn_s_setprio(0);
    if (pf) { asm volatile("s_waitcnt vmcnt(1)" ::: "memory"); }
    __builtin_amdgcn_s_barrier();
    __builtin_amdgcn_sched_barrier(0);
  }

  // ---- epilogue ----
#pragma unroll
  for (int mi = 0; mi < 16; mi++) {
#pragma unroll
    for (int ni = 0; ni < 2; ni++) {
      f32x4 v = acc[mi][ni];
      int rowb = row0 + mi * 16 + l4 * 4;
      int col = col0 + wc * 32 + ni * 16 + l15;
      if (EPI == 3) {
        float* o = (float*)Out;
#pragma unroll
        for (int r = 0; r < 4; r++) o[(size_t)(rowb + r) * 4096 + col] = v[r];
      } else {
        // RoPE
        float vp[4];
#pragma unroll
        for (int r = 0; r < 4; r++) vp[r] = __shfl_xor(v[r], 1, 64);
        bool odd = lane & 1;
        int fi = (col & 127) >> 1;
#pragma unroll
        for (int r = 0; r < 4; r++) {
          int n = rowb + r, s = n >> 1;
          float c = cosT[s * 64 + fi], sn = sinT[s * 64 + fi];
          v[r] = odd ? (vp[r] * sn + v[r] * c) : (v[r] * c - vp[r] * sn);
        }
        unsigned short* o = (unsigned short*)Out;
        int hh = col >> 7, hd = col & 127;
#pragma unroll
        for (int r = 0; r < 4; r++) {
          int n = rowb + r, s = n >> 1, b = n & 1;
          o[((size_t)(b * 32 + hh) * 2048 + s) * 128 + hd] = f2bf(v[r]);
        }
      }
    }
  }
}

// ---------------- GEMM: C[M,N] = A[M,K] @ B[N,K]^T, bf16 in, epilogues ----
// EPI: 0 = Q (rope, store [b][32+h][s][hd]), 1 = K (rope, store [b][8][s][hd]),
//      2 = V (store transposed [b][8][hd][s]),  3 = O (store fp32 token-major)
template <int EPI, int N, bool B_FP32>
__global__ __launch_bounds__(256, 2)
void gemm_bt(const unsigned short* __restrict__ A,
             const float* __restrict__ Bw32,
             const unsigned short* __restrict__ Bw16,
             void* __restrict__ Out,
             const float* __restrict__ cosT,
             const float* __restrict__ sinT) {
  const int K = KDIM;
  const int tid = threadIdx.x;
  const int lane = tid & 63, wid = tid >> 6;
  const int l15 = lane & 15, l4 = lane >> 4;
  const int nct = N / 128;
  const int ct = blockIdx.x % nct, rt = blockIdx.x / nct;
  const int row0 = rt * 128, col0 = ct * 128;
  const int wr = wid >> 1, wc = wid & 1;

  __shared__ __align__(16) unsigned short As[128 * 32];
  __shared__ __align__(16) unsigned short Bs[128 * 32];

  f32x4 acc[4][4];
#pragma unroll
  for (int i = 0; i < 4; i++)
#pragma unroll
    for (int j = 0; j < 4; j++) acc[i][j] = f32x4{0.f, 0.f, 0.f, 0.f};

  for (int kt = 0; kt < K; kt += 32) {
#pragma unroll
    for (int i = 0; i < 2; i++) {
      int j = wid * 2 + i;
      int ch = j * 64 + lane;
      int r = ch >> 2, c = ch & 3;
      int sc = c ^ ((r >> 1) & 3);
      gload_lds16(A + (size_t)(row0 + r) * K + kt + sc * 8, (char*)As + j * 1024);
    }
    if (B_FP32) {
#pragma unroll
      for (int j = 0; j < 2; j++) {
        int ch = tid + 256 * j;
        int r = ch >> 2, c = ch & 3;
        const float* src = Bw32 + (size_t)(col0 + r) * K + kt + c * 8;
        f32x4 f0 = *(const f32x4*)(src);
        f32x4 f1 = *(const f32x4*)(src + 4);
        s16x8 v;
        v[0] = (short)f2bf(f0[0]); v[1] = (short)f2bf(f0[1]);
        v[2] = (short)f2bf(f0[2]); v[3] = (short)f2bf(f0[3]);
        v[4] = (short)f2bf(f1[0]); v[5] = (short)f2bf(f1[1]);
        v[6] = (short)f2bf(f1[2]); v[7] = (short)f2bf(f1[3]);
        int sw = c ^ ((r >> 1) & 3);
        *(s16x8*)((char*)Bs + r * 64 + sw * 16) = v;
      }
    } else {
#pragma unroll
      for (int i = 0; i < 2; i++) {
        int j = wid * 2 + i;
        int ch = j * 64 + lane;
        int r = ch >> 2, c = ch & 3;
        int sc = c ^ ((r >> 1) & 3);
        gload_lds16(Bw16 + (size_t)(col0 + r) * K + kt + sc * 8, (char*)Bs + j * 1024);
      }
    }
    __syncthreads();

    s16x8 af[4], bfr[4];
#pragma unroll
    for (int mi = 0; mi < 4; mi++) {
      int r = wr * 64 + mi * 16 + l15;
      int sw = l4 ^ ((r >> 1) & 3);
      af[mi] = *(const s16x8*)((char*)As + r * 64 + sw * 16);
    }
#pragma unroll
    for (int ni = 0; ni < 4; ni++) {
      int r = wc * 64 + ni * 16 + l15;
      int sw = l4 ^ ((r >> 1) & 3);
      bfr[ni] = *(const s16x8*)((char*)Bs + r * 64 + sw * 16);
    }
#pragma unroll
    for (int mi = 0; mi < 4; mi++)
#pragma unroll
      for (int ni = 0; ni < 4; ni++)
        acc[mi][ni] = mfma_bf16(af[mi], bfr[ni], acc[mi][ni]);
    __syncthreads();
  }

#pragma unroll
  for (int mi = 0; mi < 4; mi++) {
#pragma unroll
    for (int ni = 0; ni < 4; ni++) {
      f32x4 v = acc[mi][ni];
      int rowb = row0 + wr * 64 + mi * 16 + l4 * 4;
      int col = col0 + wc * 64 + ni * 16 + l15;
      if (EPI == 3) {
        float* o = (float*)Out;
#pragma unroll
        for (int r = 0; r < 4; r++) o[(size_t)(rowb + r) * 4096 + col] = v[r];
      } else {
        if (EPI != 2) {
          float vp[4];
#pragma unroll
          for (int r = 0; r < 4; r++) vp[r] = __shfl_xor(v[r], 1, 64);
          bool odd = lane & 1;
          int fi = (col & 127) >> 1;
#pragma unroll
          for (int r = 0; r < 4; r++) {
            int n = rowb + r, s = n >> 1;
            float c = cosT[s * 64 + fi], sn = sinT[s * 64 + fi];
            v[r] = odd ? (vp[r] * sn + v[r] * c) : (v[r] * c - vp[r] * sn);
          }
        }
        unsigned short* o = (unsigned short*)Out;
        int hh = col >> 7, hd = col & 127;
#pragma unroll
        for (int r = 0; r < 4; r++) {
          int n = rowb + r, s = n >> 1, b = n & 1;
          size_t idx;
          if (EPI == 0)      idx = ((size_t)(b * 32 + hh) * 2048 + s) * 128 + hd;
          else if (EPI == 1) idx = ((size_t)(b * 8 + hh) * 2048 + s) * 128 + hd;
          else               idx = ((size_t)(b * 8 + hh) * 128 + hd) * 2048 + s;
          o[idx] = f2bf(v[r]);
        }
      }
    }
  }
}

// ---------------- Flash attention (causal, GQA) ----------------
__global__ __launch_bounds__(256, 2)
void attn_fwd(const unsigned short* __restrict__ Qa,
              const unsigned short* __restrict__ Ka,
              const unsigned short* __restrict__ Vt,
              unsigned short* __restrict__ AO) {
  int bid = blockIdx.x;
  int pid = bid & 7;
  int h = (bid >> 3) & 31;
  int b = bid >> 8;
  int kvh = h >> 2;
  int tid = threadIdx.x, lane = tid & 63, wid = tid >> 6;
  int l15 = lane & 15, l4 = lane >> 4;

  __shared__ __align__(16) unsigned short Ks[64 * 128];
  __shared__ __align__(16) unsigned short Vs[128 * 64];
  __shared__ __align__(16) unsigned short Ps[4][32 * 64];

  const unsigned short* Qp = Qa + ((size_t)(b * 32 + h) * 2048) * 128;
  const unsigned short* Kp = Ka + ((size_t)(b * 8 + kvh) * 2048) * 128;
  const unsigned short* Vp = Vt + ((size_t)(b * 8 + kvh) * 128) * 2048;

  for (int half = 0; half < 2; half++) {
    int qt = half == 0 ? (7 - pid) : (8 + pid);
    int q0 = qt * 128, qr0 = q0 + wid * 32;

    s16x8 qf[2][4];
#pragma unroll
    for (int mi = 0; mi < 2; mi++)
#pragma unroll
      for (int ks = 0; ks < 4; ks++)
        qf[mi][ks] = *(const s16x8*)(Qp + (size_t)(qr0 + mi * 16 + l15) * 128 +
                                     ks * 32 + l4 * 8);

    f32x4 o[2][8];
#pragma unroll
    for (int mi = 0; mi < 2; mi++)
#pragma unroll
      for (int nb = 0; nb < 8; nb++) o[mi][nb] = f32x4{0.f, 0.f, 0.f, 0.f};
    float m[2][4], lsum[2][4];
#pragma unroll
    for (int mi = 0; mi < 2; mi++)
#pragma unroll
      for (int pr = 0; pr < 4; pr++) { m[mi][pr] = -1e30f; lsum[mi][pr] = 0.f; }

    int nt = q0 / 64 + 2;
    for (int t = 0; t < nt; t++) {
      int s0 = t * 64;
      const unsigned short* ktp = Kp + (size_t)s0 * 128;
#pragma unroll
      for (int i = 0; i < 4; i++) {
        int j = wid * 4 + i;
        int ch = j * 64 + lane;
        {
          int r = ch >> 4, cl = ch & 15;
          int sc = (cl & 8) | ((cl ^ (r & 7)) & 7);
          gload_lds16(ktp + r * 128 + sc * 8, (char*)Ks + j * 1024);
        }
        {
          int r = ch >> 3, p = ch & 7;
          int sc = p ^ (r & 7);
          gload_lds16(Vp + (size_t)r * 2048 + s0 + sc * 8, (char*)Vs + j * 1024);
        }
      }
      __syncthreads();

      if (s0 <= qr0 + 31) {
        f32x4 sc[2][4];
#pragma unroll
        for (int mi = 0; mi < 2; mi++)
#pragma unroll
          for (int kb = 0; kb < 4; kb++) sc[mi][kb] = f32x4{0.f, 0.f, 0.f, 0.f};
#pragma unroll
        for (int kb = 0; kb < 4; kb++) {
          int r = kb * 16 + l15;
#pragma unroll
          for (int ks = 0; ks < 4; ks++) {
            int c = ks * 4 + l4;
            int sw = (c & 8) | ((c ^ (r & 7)) & 7);
            s16x8 kf = *(const s16x8*)((char*)Ks + r * 256 + sw * 16);
            sc[0][kb] = mfma_bf16(qf[0][ks], kf, sc[0][kb]);
            sc[1][kb] = mfma_bf16(qf[1][ks], kf, sc[1][kb]);
          }
        }
        bool needmask = (s0 + 63) > qr0;
#pragma unroll
        for (int mi = 0; mi < 2; mi++) {
          if (needmask) {
#pragma unroll
            for (int kb = 0; kb < 4; kb++) {
              int kg = s0 + kb * 16 + l15;
#pragma unroll
              for (int pr = 0; pr < 4; pr++) {
                int qg = qr0 + mi * 16 + l4 * 4 + pr;
                if (kg > qg) sc[mi][kb][pr] = -1e30f;
              }
            }
          }
          float rm[4];
#pragma unroll
          for (int pr = 0; pr < 4; pr++)
            rm[pr] = fmaxf(fmaxf(sc[mi][0][pr], sc[mi][1][pr]),
                           fmaxf(sc[mi][2][pr], sc[mi][3][pr]));
#pragma unroll
          for (int xm = 1; xm <= 8; xm <<= 1)
#pragma unroll
            for (int pr = 0; pr < 4; pr++)
              rm[pr] = fmaxf(rm[pr], __shfl_xor(rm[pr], xm, 64));
          bool grow = false;
#pragma unroll
          for (int pr = 0; pr < 4; pr++)
            grow = grow || ((rm[pr] - m[mi][pr]) * CSOFT > 8.f);
          if (__any(grow)) {
            float fac[4];
#pragma unroll
            for (int pr = 0; pr < 4; pr++) {
              float nm = fmaxf(m[mi][pr], rm[pr]);
              fac[pr] = __builtin_amdgcn_exp2f((m[mi][pr] - nm) * CSOFT);
              m[mi][pr] = nm;
              lsum[mi][pr] *= fac[pr];
            }
#pragma unroll
            for (int nb = 0; nb < 8; nb++)
#pragma unroll
              for (int pr = 0; pr < 4; pr++) o[mi][nb][pr] *= fac[pr];
          }
          float rs[4] = {0.f, 0.f, 0.f, 0.f};
#pragma unroll
          for (int kb = 0; kb < 4; kb++)
#pragma unroll
            for (int pr = 0; pr < 4; pr++) {
              float p = __builtin_amdgcn_exp2f((sc[mi][kb][pr] - m[mi][pr]) * CSOFT);
              sc[mi][kb][pr] = p;
              rs[pr] += p;
            }
#pragma unroll
          for (int xm = 1; xm <= 8; xm <<= 1)
#pragma unroll
            for (int pr = 0; pr < 4; pr++) rs[pr] += __shfl_xor(rs[pr], xm, 64);
#pragma unroll
          for (int pr = 0; pr < 4; pr++) lsum[mi][pr] += rs[pr];
          char* pb = (char*)(&Ps[wid][0]);
#pragma unroll
          for (int kb = 0; kb < 4; kb++) {
            int col = kb * 16 + l15;
#pragma unroll
            for (int pr = 0; pr < 4; pr++) {
              int row = mi * 16 + l4 * 4 + pr;
              *(unsigned short*)(pb + row * 128 + (((col >> 3) ^ (row & 7)) * 16) +
                                 (col & 7) * 2) = f2bf(sc[mi][kb][pr]);
            }
          }
        }
        char* pb = (char*)(&Ps[wid][0]);
#pragma unroll
        for (int ks = 0; ks < 2; ks++) {
          s16x8 pa[2];
#pragma unroll
          for (int mi = 0; mi < 2; mi++) {
            int row = mi * 16 + l15;
            int c = ks * 4 + l4;
            pa[mi] = *(const s16x8*)(pb + row * 128 + ((c ^ (row & 7)) * 16));
          }
#pragma unroll
          for (int nb = 0; nb < 8; nb++) {
            int r = nb * 16 + l15;
            int c = ks * 4 + l4;
            s16x8 vf = *(const s16x8*)((char*)Vs + r * 128 + ((c ^ (r & 7)) * 16));
            o[0][nb] = mfma_bf16(pa[0], vf, o[0][nb]);
            o[1][nb] = mfma_bf16(pa[1], vf, o[1][nb]);
          }
        }
      }
      __syncthreads();
    }

#pragma unroll
    for (int mi = 0; mi < 2; mi++) {
      float inv[4];
#pragma unroll
      for (int pr = 0; pr < 4; pr++) inv[pr] = 1.f / lsum[mi][pr];
#pragma unroll
      for (int nb = 0; nb < 8; nb++) {
        int col = h * 128 + nb * 16 + l15;
#pragma unroll
        for (int pr = 0; pr < 4; pr++) {
          int q = qr0 + mi * 16 + l4 * 4 + pr;
          AO[(size_t)(q * 2 + b) * 4096 + col] = f2bf(o[mi][nb][pr] * inv[pr]);
        }
      }
    }
  }
}

// ---------------- launch ----------------
extern "C" void kernel_launch(void* const* d_in, const int* in_sizes, int n_in,
                              void* d_out, int out_size, void* d_ws, size_t ws_size,
                              hipStream_t stream) {
  const float* x = (const float*)d_in[0];
  const float* cosT = (const float*)d_in[2];
  const float* sinT = (const float*)d_in[3];
  const float* wq = (const float*)d_in[4];
  const float* wk = (const float*)d_in[5];
  const float* wv = (const float*)d_in[6];
  const float* wo = (const float*)d_in[7];
  float* out = (float*)d_out;

  char* ws = (char*)d_ws;
  unsigned short* xb = (unsigned short*)(ws);
  unsigned short* Qa = (unsigned short*)(ws + 33554432ull);
  unsigned short* Ka = (unsigned short*)(ws + 67108864ull);
  unsigned short* Vt = (unsigned short*)(ws + 75497472ull);
  unsigned short* AO = (unsigned short*)(ws + 83886080ull);
  unsigned short* wqb = (unsigned short*)(ws + 117440512ull);
  unsigned short* wkb = (unsigned short*)(ws + 150994944ull);
  unsigned short* wvb = (unsigned short*)(ws + 159383552ull);
  unsigned short* wob = (unsigned short*)(ws + 167772160ull);
  bool wcvt = ws_size >= 201326592ull;

  cvt_bf16<<<8192, 256, 0, stream>>>(x, xb, 2097152);
  if (wcvt) {
    cvt_bf16<<<8192, 256, 0, stream>>>(wq, wqb, 2097152);
    cvt_bf16<<<2048, 256, 0, stream>>>(wk, wkb, 524288);
    cvt_bf16<<<2048, 256, 0, stream>>>(wv, wvb, 524288);
    cvt_bf16<<<8192, 256, 0, stream>>>(wo, wob, 2097152);
    gemm256<0><<<256, 512, 0, stream>>>(xb, wqb, Qa, cosT, sinT);
    gemm_bt<1, 1024, false><<<256, 256, 0, stream>>>(xb, nullptr, wkb, Ka, cosT, sinT);
    gemm_bt<2, 1024, false><<<256, 256, 0, stream>>>(xb, nullptr, wvb, Vt, cosT, sinT);
  } else {
    gemm_bt<0, 4096, true><<<1024, 256, 0, stream>>>(xb, wq, nullptr, Qa, cosT, sinT);
    gemm_bt<1, 1024, true><<<256, 256, 0, stream>>>(xb, wk, nullptr, Ka, cosT, sinT);
    gemm_bt<2, 1024, true><<<256, 256, 0, stream>>>(xb, wv, nullptr, Vt, cosT, sinT);
  }
  attn_fwd<<<512, 256, 0, stream>>>(Qa, Ka, Vt, AO);
  if (wcvt) {
    gemm256<3><<<256, 512, 0, stream>>>(AO, wob, out, cosT, sinT);
  } else {
    gemm_bt<3, 4096, true><<<1024, 256, 0, stream>>>(AO, wo, nullptr, out, cosT, sinT);
  }
}

// Round 4
// 620.090 us; speedup vs baseline: 1.2640x; 1.0336x over previous
//
#include <hip/hip_runtime.h>

typedef __attribute__((ext_vector_type(8))) short s16x8;
typedef __attribute__((ext_vector_type(8))) __bf16 bf16x8;
typedef __attribute__((ext_vector_type(4))) float f32x4;

#define S_LEN 2048
#define KDIM  4096
// softmax scale * log2(e): (1/sqrt(128)) * 1.4426950408889634
#define CSOFT 0.12751743f

__device__ __forceinline__ unsigned short f2bf(float f) {
  unsigned u = __builtin_bit_cast(unsigned, f);
  u += 0x7fffu + ((u >> 16) & 1u);
  return (unsigned short)(u >> 16);
}

__device__ __forceinline__ f32x4 mfma_bf16(s16x8 a, s16x8 b, f32x4 c) {
  return __builtin_amdgcn_mfma_f32_16x16x32_bf16(
      __builtin_bit_cast(bf16x8, a), __builtin_bit_cast(bf16x8, b), c, 0, 0, 0);
}

// async global->LDS, 16B per lane. lds ptr must be wave-uniform; g is per-lane.
__device__ __forceinline__ void gload_lds16(const unsigned short* g, void* l) {
  __builtin_amdgcn_global_load_lds(
      (const __attribute__((address_space(1))) void*)g,
      (__attribute__((address_space(3))) void*)l, 16, 0, 0);
}

// ---------------- fp32 -> bf16 convert ----------------
__global__ void cvt_bf16(const float* __restrict__ in,
                         unsigned short* __restrict__ out, int n8) {
  int i = blockIdx.x * 256 + threadIdx.x;
  if (i >= n8) return;
  const float* p = in + (size_t)i * 8;
  f32x4 a = *(const f32x4*)(p);
  f32x4 b = *(const f32x4*)(p + 4);
  s16x8 v;
  v[0] = (short)f2bf(a[0]); v[1] = (short)f2bf(a[1]);
  v[2] = (short)f2bf(a[2]); v[3] = (short)f2bf(a[3]);
  v[4] = (short)f2bf(b[0]); v[5] = (short)f2bf(b[1]);
  v[6] = (short)f2bf(b[2]); v[7] = (short)f2bf(b[3]);
  *(s16x8*)(out + (size_t)i * 8) = v;
}

// ============ 256x256 BK=64 8-wave 4-phase pipelined GEMM (m201-style) =====
// C[4096,4096] = A @ B^T (bf16 row-major [*,4096]).
// Waves 2Mx4N: wave (wr,wc) owns rows wr*128..+128, cols wc*64..+64.
// LDS: As[2 buf][2 half][128*64], Bs same = 128 KiB total. Swizzle: 16B-chunk
//   c' = c ^ (row&7); staged linearly via gload_lds with inverse-swz source.
// Per K-tile (BK=64): 4 phases x 16 MFMA (quadrants (0,0),(0,1),(1,1),(1,0));
//   ds_reads 12/4/8/0; stage 1 half-tile per phase at distance 2 tiles:
//   p1:(t+1).Ah1  p2:(t+1).Bh0  p3:(t+1).Bh1  p4:(t+2).Ah0.
//   ONE s_waitcnt vmcnt(2) per tile at p4-end (up to 5 halves in flight).
// Tail peeled: tau=62 stages 3 halves + vmcnt(0); tau=63 pure compute.
template <int EPI>
__global__ __launch_bounds__(512, 1)
void gemm256(const unsigned short* __restrict__ A,
             const unsigned short* __restrict__ B,
             void* __restrict__ Out,
             const float* __restrict__ cosT,
             const float* __restrict__ sinT) {
  const int K = KDIM;
  __shared__ __align__(16) unsigned short As[2 * 2 * 8192];
  __shared__ __align__(16) unsigned short Bs[2 * 2 * 8192];

  const int tid = threadIdx.x;
  const int lane = tid & 63, wid = tid >> 6;
  const int l15 = lane & 15, l4 = lane >> 4;
  const int wr = wid >> 2, wc = wid & 3;

  // XCD-aware bijective swizzle (256 blocks, 8 XCDs)
  int bid = blockIdx.x;
  int wg = (bid & 7) * 32 + (bid >> 3);
  const int rt = wg >> 4, ct = wg & 15;
  const int row0 = rt * 256, col0 = ct * 256;

  // staging source (pre-swizzled): chunk ch -> row=ch>>3, c=ch&7; src col
  // u = c ^ (row&7)
  const int ch0 = tid, ch1 = 512 + tid;
  const int sr0 = ch0 >> 3, u0 = (ch0 & 7) ^ (sr0 & 7);
  const int sr1 = ch1 >> 3, u1 = (ch1 & 7) ^ (sr1 & 7);
  const unsigned short* A0p = A + (size_t)(row0 + sr0) * K + u0 * 8;
  const unsigned short* A1p = A + (size_t)(row0 + sr1) * K + u1 * 8;
  const unsigned short* B0p = B + (size_t)(col0 + sr0) * K + u0 * 8;
  const unsigned short* B1p = B + (size_t)(col0 + sr1) * K + u1 * 8;

  // read-side byte offsets within a half (row l15 + frag row-mult added via
  // immediate): chunk = (kk*4 + l4) ^ (l15&7)
  const int rdo0 = l15 * 128 + ((l4 ^ (l15 & 7)) << 4);
  const int rdo1 = l15 * 128 + (((4 | l4) ^ (l15 & 7)) << 4);

  f32x4 acc[8][4];
#pragma unroll
  for (int m = 0; m < 8; m++)
#pragma unroll
    for (int n = 0; n < 4; n++) acc[m][n] = f32x4{0.f, 0.f, 0.f, 0.f};

  auto stageA = [&](int buf, int h, int kt) {
    char* d = (char*)As + buf * 32768 + h * 16384 + wid * 1024;
    size_t so = (size_t)h * 128 * K + kt;
    gload_lds16(A0p + so, d);
    gload_lds16(A1p + so, d + 8192);
  };
  auto stageB = [&](int buf, int h, int kt) {
    char* d = (char*)Bs + buf * 32768 + h * 16384 + wid * 1024;
    size_t so = (size_t)h * 128 * K + kt;
    gload_lds16(B0p + so, d);
    gload_lds16(B1p + so, d + 8192);
  };
  auto barsb = [&]() {
    __builtin_amdgcn_s_barrier();
    __builtin_amdgcn_sched_barrier(0);
  };

  // prologue: tile0 full + tile1.Ah0; wait all but newest half
  stageA(0, 0, 0);
  stageA(0, 1, 0);
  stageB(0, 0, 0);
  stageB(0, 1, 0);
  stageA(1, 0, 64);
  asm volatile("s_waitcnt vmcnt(2)" ::: "memory");
  barsb();

  auto do_tile = [&](int tau, bool s123, bool s4, int vmend) {
    const int buf = tau & 1;
    const char* Ab = (const char*)As + buf * 32768 + wr * 16384;
    const char* Bb = (const char*)Bs + buf * 32768 + (wc >> 1) * 16384 +
                     (wc & 1) * 8192;
    const int kt1 = (tau + 1) * 64, kt2 = (tau + 2) * 64;
    s16x8 af0[4], af1[4], bA0[2], bA1[2], bB0[2], bB1[2];

    // ---- p1: quadrant (mh0, nh0); ds 12; stage (t+1).Ah1 ----
#pragma unroll
    for (int mi = 0; mi < 4; mi++) {
      af0[mi] = *(const s16x8*)(Ab + mi * 2048 + rdo0);
      af1[mi] = *(const s16x8*)(Ab + mi * 2048 + rdo1);
    }
#pragma unroll
    for (int ni = 0; ni < 2; ni++) {
      bA0[ni] = *(const s16x8*)(Bb + ni * 2048 + rdo0);
      bA1[ni] = *(const s16x8*)(Bb + ni * 2048 + rdo1);
    }
    if (s123) stageA(buf ^ 1, 1, kt1);
    barsb();
    __builtin_amdgcn_s_setprio(1);
#pragma unroll
    for (int mi = 0; mi < 4; mi++)
#pragma unroll
      for (int ni = 0; ni < 2; ni++) {
        acc[mi][ni] = mfma_bf16(af0[mi], bA0[ni], acc[mi][ni]);
        acc[mi][ni] = mfma_bf16(af1[mi], bA1[ni], acc[mi][ni]);
      }
    __builtin_amdgcn_s_setprio(0);
    barsb();

    // ---- p2: (mh0, nh1); ds 4; stage (t+1).Bh0 ----
#pragma unroll
    for (int ni = 0; ni < 2; ni++) {
      bB0[ni] = *(const s16x8*)(Bb + (2 + ni) * 2048 + rdo0);
      bB1[ni] = *(const s16x8*)(Bb + (2 + ni) * 2048 + rdo1);
    }
    if (s123) stageB(buf ^ 1, 0, kt1);
    barsb();
    __builtin_amdgcn_s_setprio(1);
#pragma unroll
    for (int mi = 0; mi < 4; mi++)
#pragma unroll
      for (int ni = 0; ni < 2; ni++) {
        acc[mi][2 + ni] = mfma_bf16(af0[mi], bB0[ni], acc[mi][2 + ni]);
        acc[mi][2 + ni] = mfma_bf16(af1[mi], bB1[ni], acc[mi][2 + ni]);
      }
    __builtin_amdgcn_s_setprio(0);
    barsb();

    // ---- p3: (mh1, nh1); ds 8; stage (t+1).Bh1 ----
#pragma unroll
    for (int mi = 0; mi < 4; mi++) {
      af0[mi] = *(const s16x8*)(Ab + 8192 + mi * 2048 + rdo0);
      af1[mi] = *(const s16x8*)(Ab + 8192 + mi * 2048 + rdo1);
    }
    if (s123) stageB(buf ^ 1, 1, kt1);
    barsb();
    __builtin_amdgcn_s_setprio(1);
#pragma unroll
    for (int mi = 0; mi < 4; mi++)
#pragma unroll
      for (int ni = 0; ni < 2; ni++) {
        acc[4 + mi][2 + ni] = mfma_bf16(af0[mi], bB0[ni], acc[4 + mi][2 + ni]);
        acc[4 + mi][2 + ni] = mfma_bf16(af1[mi], bB1[ni], acc[4 + mi][2 + ni]);
      }
    __builtin_amdgcn_s_setprio(0);
    barsb();

    // ---- p4: (mh1, nh0); ds 0; stage (t+2).Ah0; tile-boundary vmcnt ----
    if (s4) stageA(buf, 0, kt2);
    barsb();
    __builtin_amdgcn_s_setprio(1);
#pragma unroll
    for (int mi = 0; mi < 4; mi++)
#pragma unroll
      for (int ni = 0; ni < 2; ni++) {
        acc[4 + mi][ni] = mfma_bf16(af0[mi], bA0[ni], acc[4 + mi][ni]);
        acc[4 + mi][ni] = mfma_bf16(af1[mi], bA1[ni], acc[4 + mi][ni]);
      }
    __builtin_amdgcn_s_setprio(0);
    if (vmend == 2) {
      asm volatile("s_waitcnt vmcnt(2)" ::: "memory");
    } else if (vmend == 0) {
      asm volatile("s_waitcnt vmcnt(0)" ::: "memory");
    }
    barsb();
  };

  for (int tau = 0; tau < 62; tau++) do_tile(tau, true, true, 2);
  do_tile(62, true, false, 0);
  do_tile(63, false, false, -1);

  // ---- epilogue ----
#pragma unroll
  for (int m = 0; m < 8; m++) {
#pragma unroll
    for (int n = 0; n < 4; n++) {
      f32x4 v = acc[m][n];
      int rowb = row0 + wr * 128 + m * 16 + l4 * 4;
      int col = col0 + wc * 64 + n * 16 + l15;
      if (EPI == 3) {
        float* o = (float*)Out;
#pragma unroll
        for (int r = 0; r < 4; r++) o[(size_t)(rowb + r) * 4096 + col] = v[r];
      } else {
        // RoPE
        float vp[4];
#pragma unroll
        for (int r = 0; r < 4; r++) vp[r] = __shfl_xor(v[r], 1, 64);
        bool odd = lane & 1;
        int fi = (col & 127) >> 1;
#pragma unroll
        for (int r = 0; r < 4; r++) {
          int nn = rowb + r, s = nn >> 1;
          float c = cosT[s * 64 + fi], sn = sinT[s * 64 + fi];
          v[r] = odd ? (vp[r] * sn + v[r] * c) : (v[r] * c - vp[r] * sn);
        }
        unsigned short* o = (unsigned short*)Out;
        int hh = col >> 7, hd = col & 127;
#pragma unroll
        for (int r = 0; r < 4; r++) {
          int nn = rowb + r, s = nn >> 1, b = nn & 1;
          o[((size_t)(b * 32 + hh) * 2048 + s) * 128 + hd] = f2bf(v[r]);
        }
      }
    }
  }
}

// ---------------- GEMM: C[M,N] = A[M,K] @ B[N,K]^T, bf16 in, epilogues ----
// EPI: 0 = Q (rope, store [b][32+h][s][hd]), 1 = K (rope, store [b][8][s][hd]),
//      2 = V (store transposed [b][8][hd][s]),  3 = O (store fp32 token-major)
template <int EPI, int N, bool B_FP32>
__global__ __launch_bounds__(256, 2)
void gemm_bt(const unsigned short* __restrict__ A,
             const float* __restrict__ Bw32,
             const unsigned short* __restrict__ Bw16,
             void* __restrict__ Out,
             const float* __restrict__ cosT,
             const float* __restrict__ sinT) {
  const int K = KDIM;
  const int tid = threadIdx.x;
  const int lane = tid & 63, wid = tid >> 6;
  const int l15 = lane & 15, l4 = lane >> 4;
  const int nct = N / 128;
  const int ct = blockIdx.x % nct, rt = blockIdx.x / nct;
  const int row0 = rt * 128, col0 = ct * 128;
  const int wr = wid >> 1, wc = wid & 1;

  __shared__ __align__(16) unsigned short As[128 * 32];
  __shared__ __align__(16) unsigned short Bs[128 * 32];

  f32x4 acc[4][4];
#pragma unroll
  for (int i = 0; i < 4; i++)
#pragma unroll
    for (int j = 0; j < 4; j++) acc[i][j] = f32x4{0.f, 0.f, 0.f, 0.f};

  for (int kt = 0; kt < K; kt += 32) {
#pragma unroll
    for (int i = 0; i < 2; i++) {
      int j = wid * 2 + i;
      int ch = j * 64 + lane;
      int r = ch >> 2, c = ch & 3;
      int sc = c ^ ((r >> 1) & 3);
      gload_lds16(A + (size_t)(row0 + r) * K + kt + sc * 8, (char*)As + j * 1024);
    }
    if (B_FP32) {
#pragma unroll
      for (int j = 0; j < 2; j++) {
        int ch = tid + 256 * j;
        int r = ch >> 2, c = ch & 3;
        const float* src = Bw32 + (size_t)(col0 + r) * K + kt + c * 8;
        f32x4 f0 = *(const f32x4*)(src);
        f32x4 f1 = *(const f32x4*)(src + 4);
        s16x8 v;
        v[0] = (short)f2bf(f0[0]); v[1] = (short)f2bf(f0[1]);
        v[2] = (short)f2bf(f0[2]); v[3] = (short)f2bf(f0[3]);
        v[4] = (short)f2bf(f1[0]); v[5] = (short)f2bf(f1[1]);
        v[6] = (short)f2bf(f1[2]); v[7] = (short)f2bf(f1[3]);
        int sw = c ^ ((r >> 1) & 3);
        *(s16x8*)((char*)Bs + r * 64 + sw * 16) = v;
      }
    } else {
#pragma unroll
      for (int i = 0; i < 2; i++) {
        int j = wid * 2 + i;
        int ch = j * 64 + lane;
        int r = ch >> 2, c = ch & 3;
        int sc = c ^ ((r >> 1) & 3);
        gload_lds16(Bw16 + (size_t)(col0 + r) * K + kt + sc * 8, (char*)Bs + j * 1024);
      }
    }
    __syncthreads();

    s16x8 af[4], bfr[4];
#pragma unroll
    for (int mi = 0; mi < 4; mi++) {
      int r = wr * 64 + mi * 16 + l15;
      int sw = l4 ^ ((r >> 1) & 3);
      af[mi] = *(const s16x8*)((char*)As + r * 64 + sw * 16);
    }
#pragma unroll
    for (int ni = 0; ni < 4; ni++) {
      int r = wc * 64 + ni * 16 + l15;
      int sw = l4 ^ ((r >> 1) & 3);
      bfr[ni] = *(const s16x8*)((char*)Bs + r * 64 + sw * 16);
    }
#pragma unroll
    for (int mi = 0; mi < 4; mi++)
#pragma unroll
      for (int ni = 0; ni < 4; ni++)
        acc[mi][ni] = mfma_bf16(af[mi], bfr[ni], acc[mi][ni]);
    __syncthreads();
  }

#pragma unroll
  for (int mi = 0; mi < 4; mi++) {
#pragma unroll
    for (int ni = 0; ni < 4; ni++) {
      f32x4 v = acc[mi][ni];
      int rowb = row0 + wr * 64 + mi * 16 + l4 * 4;
      int col = col0 + wc * 64 + ni * 16 + l15;
      if (EPI == 3) {
        float* o = (float*)Out;
#pragma unroll
        for (int r = 0; r < 4; r++) o[(size_t)(rowb + r) * 4096 + col] = v[r];
      } else {
        if (EPI != 2) {
          float vp[4];
#pragma unroll
          for (int r = 0; r < 4; r++) vp[r] = __shfl_xor(v[r], 1, 64);
          bool odd = lane & 1;
          int fi = (col & 127) >> 1;
#pragma unroll
          for (int r = 0; r < 4; r++) {
            int n = rowb + r, s = n >> 1;
            float c = cosT[s * 64 + fi], sn = sinT[s * 64 + fi];
            v[r] = odd ? (vp[r] * sn + v[r] * c) : (v[r] * c - vp[r] * sn);
          }
        }
        unsigned short* o = (unsigned short*)Out;
        int hh = col >> 7, hd = col & 127;
#pragma unroll
        for (int r = 0; r < 4; r++) {
          int n = rowb + r, s = n >> 1, b = n & 1;
          size_t idx;
          if (EPI == 0)      idx = ((size_t)(b * 32 + hh) * 2048 + s) * 128 + hd;
          else if (EPI == 1) idx = ((size_t)(b * 8 + hh) * 2048 + s) * 128 + hd;
          else               idx = ((size_t)(b * 8 + hh) * 128 + hd) * 2048 + s;
          o[idx] = f2bf(v[r]);
        }
      }
    }
  }
}

// ---------------- Flash attention (causal, GQA) ----------------
__global__ __launch_bounds__(256, 2)
void attn_fwd(const unsigned short* __restrict__ Qa,
              const unsigned short* __restrict__ Ka,
              const unsigned short* __restrict__ Vt,
              unsigned short* __restrict__ AO) {
  int bid = blockIdx.x;
  int pid = bid & 7;
  int h = (bid >> 3) & 31;
  int b = bid >> 8;
  int kvh = h >> 2;
  int tid = threadIdx.x, lane = tid & 63, wid = tid >> 6;
  int l15 = lane & 15, l4 = lane >> 4;

  __shared__ __align__(16) unsigned short Ks[64 * 128];
  __shared__ __align__(16) unsigned short Vs[128 * 64];
  __shared__ __align__(16) unsigned short Ps[4][32 * 64];

  const unsigned short* Qp = Qa + ((size_t)(b * 32 + h) * 2048) * 128;
  const unsigned short* Kp = Ka + ((size_t)(b * 8 + kvh) * 2048) * 128;
  const unsigned short* Vp = Vt + ((size_t)(b * 8 + kvh) * 128) * 2048;

  for (int half = 0; half < 2; half++) {
    int qt = half == 0 ? (7 - pid) : (8 + pid);
    int q0 = qt * 128, qr0 = q0 + wid * 32;

    s16x8 qf[2][4];
#pragma unroll
    for (int mi = 0; mi < 2; mi++)
#pragma unroll
      for (int ks = 0; ks < 4; ks++)
        qf[mi][ks] = *(const s16x8*)(Qp + (size_t)(qr0 + mi * 16 + l15) * 128 +
                                     ks * 32 + l4 * 8);

    f32x4 o[2][8];
#pragma unroll
    for (int mi = 0; mi < 2; mi++)
#pragma unroll
      for (int nb = 0; nb < 8; nb++) o[mi][nb] = f32x4{0.f, 0.f, 0.f, 0.f};
    float m[2][4], lsum[2][4];
#pragma unroll
    for (int mi = 0; mi < 2; mi++)
#pragma unroll
      for (int pr = 0; pr < 4; pr++) { m[mi][pr] = -1e30f; lsum[mi][pr] = 0.f; }

    int nt = q0 / 64 + 2;
    for (int t = 0; t < nt; t++) {
      int s0 = t * 64;
      const unsigned short* ktp = Kp + (size_t)s0 * 128;
#pragma unroll
      for (int i = 0; i < 4; i++) {
        int j = wid * 4 + i;
        int ch = j * 64 + lane;
        {
          int r = ch >> 4, cl = ch & 15;
          int sc = (cl & 8) | ((cl ^ (r & 7)) & 7);
          gload_lds16(ktp + r * 128 + sc * 8, (char*)Ks + j * 1024);
        }
        {
          int r = ch >> 3, p = ch & 7;
          int sc = p ^ (r & 7);
          gload_lds16(Vp + (size_t)r * 2048 + s0 + sc * 8, (char*)Vs + j * 1024);
        }
      }
      __syncthreads();

      if (s0 <= qr0 + 31) {
        f32x4 sc[2][4];
#pragma unroll
        for (int mi = 0; mi < 2; mi++)
#pragma unroll
          for (int kb = 0; kb < 4; kb++) sc[mi][kb] = f32x4{0.f, 0.f, 0.f, 0.f};
#pragma unroll
        for (int kb = 0; kb < 4; kb++) {
          int r = kb * 16 + l15;
#pragma unroll
          for (int ks = 0; ks < 4; ks++) {
            int c = ks * 4 + l4;
            int sw = (c & 8) | ((c ^ (r & 7)) & 7);
            s16x8 kf = *(const s16x8*)((char*)Ks + r * 256 + sw * 16);
            sc[0][kb] = mfma_bf16(qf[0][ks], kf, sc[0][kb]);
            sc[1][kb] = mfma_bf16(qf[1][ks], kf, sc[1][kb]);
          }
        }
        bool needmask = (s0 + 63) > qr0;
#pragma unroll
        for (int mi = 0; mi < 2; mi++) {
          if (needmask) {
#pragma unroll
            for (int kb = 0; kb < 4; kb++) {
              int kg = s0 + kb * 16 + l15;
#pragma unroll
              for (int pr = 0; pr < 4; pr++) {
                int qg = qr0 + mi * 16 + l4 * 4 + pr;
                if (kg > qg) sc[mi][kb][pr] = -1e30f;
              }
            }
          }
          float rm[4];
#pragma unroll
          for (int pr = 0; pr < 4; pr++)
            rm[pr] = fmaxf(fmaxf(sc[mi][0][pr], sc[mi][1][pr]),
                           fmaxf(sc[mi][2][pr], sc[mi][3][pr]));
#pragma unroll
          for (int xm = 1; xm <= 8; xm <<= 1)
#pragma unroll
            for (int pr = 0; pr < 4; pr++)
              rm[pr] = fmaxf(rm[pr], __shfl_xor(rm[pr], xm, 64));
          bool grow = false;
#pragma unroll
          for (int pr = 0; pr < 4; pr++)
            grow = grow || ((rm[pr] - m[mi][pr]) * CSOFT > 8.f);
          if (__any(grow)) {
            float fac[4];
#pragma unroll
            for (int pr = 0; pr < 4; pr++) {
              float nm = fmaxf(m[mi][pr], rm[pr]);
              fac[pr] = __builtin_amdgcn_exp2f((m[mi][pr] - nm) * CSOFT);
              m[mi][pr] = nm;
              lsum[mi][pr] *= fac[pr];
            }
#pragma unroll
            for (int nb = 0; nb < 8; nb++)
#pragma unroll
              for (int pr = 0; pr < 4; pr++) o[mi][nb][pr] *= fac[pr];
          }
          float rs[4] = {0.f, 0.f, 0.f, 0.f};
#pragma unroll
          for (int kb = 0; kb < 4; kb++)
#pragma unroll
            for (int pr = 0; pr < 4; pr++) {
              float p = __builtin_amdgcn_exp2f((sc[mi][kb][pr] - m[mi][pr]) * CSOFT);
              sc[mi][kb][pr] = p;
              rs[pr] += p;
            }
#pragma unroll
          for (int xm = 1; xm <= 8; xm <<= 1)
#pragma unroll
            for (int pr = 0; pr < 4; pr++) rs[pr] += __shfl_xor(rs[pr], xm, 64);
#pragma unroll
          for (int pr = 0; pr < 4; pr++) lsum[mi][pr] += rs[pr];
          char* pb = (char*)(&Ps[wid][0]);
#pragma unroll
          for (int kb = 0; kb < 4; kb++) {
            int col = kb * 16 + l15;
#pragma unroll
            for (int pr = 0; pr < 4; pr++) {
              int row = mi * 16 + l4 * 4 + pr;
              *(unsigned short*)(pb + row * 128 + (((col >> 3) ^ (row & 7)) * 16) +
                                 (col & 7) * 2) = f2bf(sc[mi][kb][pr]);
            }
          }
        }
        char* pb = (char*)(&Ps[wid][0]);
#pragma unroll
        for (int ks = 0; ks < 2; ks++) {
          s16x8 pa[2];
#pragma unroll
          for (int mi = 0; mi < 2; mi++) {
            int row = mi * 16 + l15;
            int c = ks * 4 + l4;
            pa[mi] = *(const s16x8*)(pb + row * 128 + ((c ^ (row & 7)) * 16));
          }
#pragma unroll
          for (int nb = 0; nb < 8; nb++) {
            int r = nb * 16 + l15;
            int c = ks * 4 + l4;
            s16x8 vf = *(const s16x8*)((char*)Vs + r * 128 + ((c ^ (r & 7)) * 16));
            o[0][nb] = mfma_bf16(pa[0], vf, o[0][nb]);
            o[1][nb] = mfma_bf16(pa[1], vf, o[1][nb]);
          }
        }
      }
      __syncthreads();
    }

#pragma unroll
    for (int mi = 0; mi < 2; mi++) {
      float inv[4];
#pragma unroll
      for (int pr = 0; pr < 4; pr++) inv[pr] = 1.f / lsum[mi][pr];
#pragma unroll
      for (int nb = 0; nb < 8; nb++) {
        int col = h * 128 + nb * 16 + l15;
#pragma unroll
        for (int pr = 0; pr < 4; pr++) {
          int q = qr0 + mi * 16 + l4 * 4 + pr;
          AO[(size_t)(q * 2 + b) * 4096 + col] = f2bf(o[mi][nb][pr] * inv[pr]);
        }
      }
    }
  }
}

// ---------------- launch ----------------
extern "C" void kernel_launch(void* const* d_in, const int* in_sizes, int n_in,
                              void* d_out, int out_size, void* d_ws, size_t ws_size,
                              hipStream_t stream) {
  const float* x = (const float*)d_in[0];
  const float* cosT = (const float*)d_in[2];
  const float* sinT = (const float*)d_in[3];
  const float* wq = (const float*)d_in[4];
  const float* wk = (const float*)d_in[5];
  const float* wv = (const float*)d_in[6];
  const float* wo = (const float*)d_in[7];
  float* out = (float*)d_out;

  char* ws = (char*)d_ws;
  unsigned short* xb = (unsigned short*)(ws);
  unsigned short* Qa = (unsigned short*)(ws + 33554432ull);
  unsigned short* Ka = (unsigned short*)(ws + 67108864ull);
  unsigned short* Vt = (unsigned short*)(ws + 75497472ull);
  unsigned short* AO = (unsigned short*)(ws + 83886080ull);
  unsigned short* wqb = (unsigned short*)(ws + 117440512ull);
  unsigned short* wkb = (unsigned short*)(ws + 150994944ull);
  unsigned short* wvb = (unsigned short*)(ws + 159383552ull);
  unsigned short* wob = (unsigned short*)(ws + 167772160ull);
  bool wcvt = ws_size >= 201326592ull;

  cvt_bf16<<<8192, 256, 0, stream>>>(x, xb, 2097152);
  if (wcvt) {
    cvt_bf16<<<8192, 256, 0, stream>>>(wq, wqb, 2097152);
    cvt_bf16<<<2048, 256, 0, stream>>>(wk, wkb, 524288);
    cvt_bf16<<<2048, 256, 0, stream>>>(wv, wvb, 524288);
    cvt_bf16<<<8192, 256, 0, stream>>>(wo, wob, 2097152);
    gemm256<0><<<256, 512, 0, stream>>>(xb, wqb, Qa, cosT, sinT);
    gemm_bt<1, 1024, false><<<256, 256, 0, stream>>>(xb, nullptr, wkb, Ka, cosT, sinT);
    gemm_bt<2, 1024, false><<<256, 256, 0, stream>>>(xb, nullptr, wvb, Vt, cosT, sinT);
  } else {
    gemm_bt<0, 4096, true><<<1024, 256, 0, stream>>>(xb, wq, nullptr, Qa, cosT, sinT);
    gemm_bt<1, 1024, true><<<256, 256, 0, stream>>>(xb, wk, nullptr, Ka, cosT, sinT);
    gemm_bt<2, 1024, true><<<256, 256, 0, stream>>>(xb, wv, nullptr, Vt, cosT, sinT);
  }
  attn_fwd<<<512, 256, 0, stream>>>(Qa, Ka, Vt, AO);
  if (wcvt) {
    gemm256<3><<<256, 512, 0, stream>>>(AO, wob, out, cosT, sinT);
  } else {
    gemm_bt<3, 4096, true><<<1024, 256, 0, stream>>>(AO, wo, nullptr, out, cosT, sinT);
  }
}